// Round 1
// baseline (616.942 us; speedup 1.0000x reference)
//
#include <hip/hip_runtime.h>

constexpr int NUM_GRAPHS = 64;
constexpr int OUT_DIM = 64;

// ---------------- CSR build ----------------

__global__ void count_edges_k(const int* __restrict__ dst, int E, int* __restrict__ cnt) {
    int e = blockIdx.x * 256 + threadIdx.x;
    if (e < E) atomicAdd(&cnt[dst[e]], 1);
}

__global__ void dinv_k(const int* __restrict__ cnt, float* __restrict__ dinv, int n) {
    int i = blockIdx.x * 256 + threadIdx.x;
    if (i < n) dinv[i] = rsqrtf((float)(cnt[i] + 1));  // +1 self-loop
}

__global__ void scan_part_k(const int* __restrict__ cnt, int n, int* __restrict__ bsum) {
    __shared__ int s[256];
    int t = threadIdx.x;
    int i = blockIdx.x * 256 + t;
    s[t] = (i < n) ? cnt[i] : 0;
    __syncthreads();
    for (int off = 128; off > 0; off >>= 1) {
        if (t < off) s[t] += s[t + off];
        __syncthreads();
    }
    if (t == 0) bsum[blockIdx.x] = s[0];
}

// single block, nb <= 256
__global__ void scan_top_k(int* __restrict__ bsum, int nb) {
    __shared__ int s[256];
    int t = threadIdx.x;
    s[t] = (t < nb) ? bsum[t] : 0;
    __syncthreads();
    for (int off = 1; off < 256; off <<= 1) {
        int v = (t >= off) ? s[t - off] : 0;
        __syncthreads();
        s[t] += v;
        __syncthreads();
    }
    int ex = (t == 0) ? 0 : s[t - 1];
    if (t < nb) bsum[t] = ex;
}

__global__ void scan_final_k(const int* __restrict__ cnt, int n, const int* __restrict__ boff,
                             int* __restrict__ rowptr, int* __restrict__ cursor) {
    __shared__ int s[256];
    int t = threadIdx.x;
    int i = blockIdx.x * 256 + t;
    int v = (i < n) ? cnt[i] : 0;
    s[t] = v;
    __syncthreads();
    for (int off = 1; off < 256; off <<= 1) {
        int u = (t >= off) ? s[t - off] : 0;
        __syncthreads();
        s[t] += u;
        __syncthreads();
    }
    int incl = s[t];
    int ex = incl - v + boff[blockIdx.x];
    if (i < n) { rowptr[i] = ex; cursor[i] = ex; }
    if (i == n - 1) rowptr[n] = ex + v;
}

__global__ void fill_csr_k(const int* __restrict__ src, const int* __restrict__ dst, int E,
                           int* __restrict__ cursor, int* __restrict__ csr_src) {
    int e = blockIdx.x * 256 + threadIdx.x;
    if (e < E) {
        int d = dst[e];
        int pos = atomicAdd(&cursor[d], 1);
        csr_src[pos] = src[e];
    }
}

// ---------------- GEMM: C[M,N] = A[M,128] @ W[128,N] (no bias) ----------------

template <int N>
__global__ __launch_bounds__(256) void gemm_k(const float* __restrict__ A, const float* __restrict__ W,
                                              float* __restrict__ C, int M) {
    constexpr int TM = 64;
    constexpr int TK = 32;
    constexpr int CT = N / 4;          // col tiles (float4): 32 or 16
    constexpr int RPT = TM * CT / 256; // rows per thread: 8 or 4
    __shared__ float As[TM][TK + 1];   // +1 pad: conflict-free column reads
    __shared__ float Ws[TK][N];

    const int tid = threadIdx.x;
    const int cx = tid % CT;
    const int ry = tid / CT;
    const int rbase = blockIdx.x * TM;

    float acc[RPT][4];
#pragma unroll
    for (int r = 0; r < RPT; r++)
#pragma unroll
        for (int c = 0; c < 4; c++) acc[r][c] = 0.f;

    for (int kk = 0; kk < 128; kk += TK) {
        __syncthreads();
        // stage A tile (scalar LDS writes due to +1 pad)
        for (int idx = tid; idx < TM * (TK / 4); idx += 256) {
            int row = idx >> 3;
            int c4 = idx & 7;
            int gr = rbase + row;
            if (gr >= M) gr = M - 1;
            float4 v = *(const float4*)(A + (size_t)gr * 128 + kk + c4 * 4);
            As[row][c4 * 4 + 0] = v.x;
            As[row][c4 * 4 + 1] = v.y;
            As[row][c4 * 4 + 2] = v.z;
            As[row][c4 * 4 + 3] = v.w;
        }
        // stage W tile
        for (int idx = tid; idx < TK * CT; idx += 256) {
            int row = idx / CT;
            int c4 = idx % CT;
            *(float4*)(&Ws[row][c4 * 4]) = *(const float4*)(W + (size_t)(kk + row) * N + c4 * 4);
        }
        __syncthreads();
        for (int k = 0; k < TK; k++) {
            float4 w = *(const float4*)(&Ws[k][cx * 4]);
#pragma unroll
            for (int r = 0; r < RPT; r++) {
                float a = As[ry * RPT + r][k];
                acc[r][0] += a * w.x;
                acc[r][1] += a * w.y;
                acc[r][2] += a * w.z;
                acc[r][3] += a * w.w;
            }
        }
    }
#pragma unroll
    for (int r = 0; r < RPT; r++) {
        int gr = rbase + ry * RPT + r;
        if (gr < M) {
            float4 o;
            o.x = acc[r][0]; o.y = acc[r][1]; o.z = acc[r][2]; o.w = acc[r][3];
            *(float4*)(C + (size_t)gr * N + cx * 4) = o;
        }
    }
}

// ---------------- Aggregation: out[i] = act(dinv[i]*sum_{s in N(i)} dinv[s]*h[s] + dinv[i]^2*h[i] + b) ----------------

template <int D, bool RELU>
__global__ __launch_bounds__(256) void aggregate_k(const float* __restrict__ h, const float* __restrict__ dinv,
                                                   const int* __restrict__ rowptr, const int* __restrict__ csr_src,
                                                   const float* __restrict__ bias, float* __restrict__ out, int n) {
    int wid = (blockIdx.x * 256 + threadIdx.x) >> 6;  // one wave per node
    int lane = threadIdx.x & 63;
    if (wid >= n) return;
    float di = dinv[wid];
    int e0 = rowptr[wid], e1 = rowptr[wid + 1];
    if (D == 128) {
        float ax = 0.f, ay = 0.f;
        for (int e = e0; e < e1; ++e) {
            int s = csr_src[e];
            float w = dinv[s];
            float2 hv = *(const float2*)(h + (size_t)s * 128 + lane * 2);
            ax += w * hv.x;
            ay += w * hv.y;
        }
        float2 hs = *(const float2*)(h + (size_t)wid * 128 + lane * 2);
        ax = di * ax + di * di * hs.x + bias[lane * 2 + 0];
        ay = di * ay + di * di * hs.y + bias[lane * 2 + 1];
        if (RELU) { ax = fmaxf(ax, 0.f); ay = fmaxf(ay, 0.f); }
        float2 o; o.x = ax; o.y = ay;
        *(float2*)(out + (size_t)wid * 128 + lane * 2) = o;
    } else {
        float a = 0.f;
        for (int e = e0; e < e1; ++e) {
            int s = csr_src[e];
            a += dinv[s] * h[(size_t)s * 64 + lane];
        }
        float hs = h[(size_t)wid * 64 + lane];
        a = di * a + di * di * hs + bias[lane];
        if (RELU) a = fmaxf(a, 0.f);
        out[(size_t)wid * 64 + lane] = a;
    }
}

// ---------------- Pooling ----------------

__global__ __launch_bounds__(256) void pool_k(const float* __restrict__ h, const int* __restrict__ batch,
                                              float* __restrict__ osum, int* __restrict__ gcnt, int n) {
    int wid = (blockIdx.x * 256 + threadIdx.x) >> 6;
    int lane = threadIdx.x & 63;
    if (wid >= n) return;
    int g = batch[wid];
    atomicAdd(&osum[g * 64 + lane], h[(size_t)wid * 64 + lane]);
    if (lane == 0) atomicAdd(&gcnt[g], 1);
}

__global__ void finalize_k(float* __restrict__ out, const int* __restrict__ gcnt) {
    int i = threadIdx.x + blockIdx.x * 256;
    if (i < NUM_GRAPHS * OUT_DIM) {
        int g = i >> 6;
        float c = (float)((gcnt[g] > 1) ? gcnt[g] : 1);
        out[i] = out[i] / c;
    }
}

// ---------------- launch ----------------

extern "C" void kernel_launch(void* const* d_in, const int* in_sizes, int n_in,
                              void* d_out, int out_size, void* d_ws, size_t ws_size,
                              hipStream_t stream) {
    const float* x = (const float*)d_in[0];
    const int* edge = (const int*)d_in[1];
    const int* batch = (const int*)d_in[2];
    const float* W1 = (const float*)d_in[3];
    const float* b1 = (const float*)d_in[4];
    const float* W2 = (const float*)d_in[5];
    const float* b2 = (const float*)d_in[6];

    const int n = in_sizes[0] / 128;
    const int E = in_sizes[1] / 2;
    const int* esrc = edge;
    const int* edst = edge + E;

    char* ws = (char*)d_ws;
    size_t off = 0;
    auto alloc = [&](size_t bytes) -> char* {
        char* p = ws + off;
        off = (off + bytes + 255) & ~(size_t)255;
        return p;
    };
    int* cnt = (int*)alloc((size_t)n * sizeof(int));
    int* rowptr = (int*)alloc((size_t)(n + 1) * sizeof(int));
    int* cursor = (int*)alloc((size_t)n * sizeof(int));
    int* bsum = (int*)alloc(256 * sizeof(int));
    int* gcnt = (int*)alloc(NUM_GRAPHS * sizeof(int));
    float* dinv = (float*)alloc((size_t)n * sizeof(float));
    int* csr_src = (int*)alloc((size_t)E * sizeof(int));
    float* bufA = (float*)alloc((size_t)n * 128 * sizeof(float));
    float* bufB = (float*)alloc((size_t)n * 128 * sizeof(float));
    (void)ws_size;

    hipMemsetAsync(cnt, 0, (size_t)n * sizeof(int), stream);
    hipMemsetAsync(gcnt, 0, NUM_GRAPHS * sizeof(int), stream);
    hipMemsetAsync(d_out, 0, NUM_GRAPHS * OUT_DIM * sizeof(float), stream);

    const int eb = (E + 255) / 256;
    const int nb = (n + 255) / 256;  // must be <= 256 for scan_top (n=50000 -> 196)

    count_edges_k<<<eb, 256, 0, stream>>>(edst, E, cnt);
    dinv_k<<<nb, 256, 0, stream>>>(cnt, dinv, n);
    scan_part_k<<<nb, 256, 0, stream>>>(cnt, n, bsum);
    scan_top_k<<<1, 256, 0, stream>>>(bsum, nb);
    scan_final_k<<<nb, 256, 0, stream>>>(cnt, n, bsum, rowptr, cursor);
    fill_csr_k<<<eb, 256, 0, stream>>>(esrc, edst, E, cursor, csr_src);

    // conv1: h1 = x @ W1 ; hagg = relu(aggregate(h1) + b1)
    gemm_k<128><<<(n + 63) / 64, 256, 0, stream>>>(x, W1, bufA, n);
    aggregate_k<128, true><<<(n + 3) / 4, 256, 0, stream>>>(bufA, dinv, rowptr, csr_src, b1, bufB, n);

    // conv2: h2 = hagg @ W2 ; out2 = aggregate(h2) + b2
    gemm_k<64><<<(n + 63) / 64, 256, 0, stream>>>(bufB, W2, bufA, n);
    aggregate_k<64, false><<<(n + 3) / 4, 256, 0, stream>>>(bufA, dinv, rowptr, csr_src, b2, bufB, n);

    // mean pool over graphs
    pool_k<<<(n + 3) / 4, 256, 0, stream>>>(bufB, batch, (float*)d_out, gcnt, n);
    finalize_k<<<(NUM_GRAPHS * OUT_DIM + 255) / 256, 256, 0, stream>>>((float*)d_out, gcnt);
}

// Round 2
// 317.882 us; speedup vs baseline: 1.9408x; 1.9408x over previous
//
#include <hip/hip_runtime.h>

constexpr int NUM_GRAPHS = 64;
constexpr int OUT_DIM = 64;

// ---------------- CSR build ----------------

__global__ void count_edges_k(const int* __restrict__ dst, int E, int* __restrict__ cnt) {
    int e = blockIdx.x * 256 + threadIdx.x;
    if (e < E) atomicAdd(&cnt[dst[e]], 1);
}

__global__ void dinv_k(const int* __restrict__ cnt, float* __restrict__ dinv, int n) {
    int i = blockIdx.x * 256 + threadIdx.x;
    if (i < n) dinv[i] = rsqrtf((float)(cnt[i] + 1));  // +1 self-loop
}

__global__ void scan_part_k(const int* __restrict__ cnt, int n, int* __restrict__ bsum) {
    __shared__ int s[256];
    int t = threadIdx.x;
    int i = blockIdx.x * 256 + t;
    s[t] = (i < n) ? cnt[i] : 0;
    __syncthreads();
    for (int off = 128; off > 0; off >>= 1) {
        if (t < off) s[t] += s[t + off];
        __syncthreads();
    }
    if (t == 0) bsum[blockIdx.x] = s[0];
}

// single block, nb <= 256
__global__ void scan_top_k(int* __restrict__ bsum, int nb) {
    __shared__ int s[256];
    int t = threadIdx.x;
    s[t] = (t < nb) ? bsum[t] : 0;
    __syncthreads();
    for (int off = 1; off < 256; off <<= 1) {
        int v = (t >= off) ? s[t - off] : 0;
        __syncthreads();
        s[t] += v;
        __syncthreads();
    }
    int ex = (t == 0) ? 0 : s[t - 1];
    if (t < nb) bsum[t] = ex;
}

__global__ void scan_final_k(const int* __restrict__ cnt, int n, const int* __restrict__ boff,
                             int* __restrict__ rowptr, int* __restrict__ cursor) {
    __shared__ int s[256];
    int t = threadIdx.x;
    int i = blockIdx.x * 256 + t;
    int v = (i < n) ? cnt[i] : 0;
    s[t] = v;
    __syncthreads();
    for (int off = 1; off < 256; off <<= 1) {
        int u = (t >= off) ? s[t - off] : 0;
        __syncthreads();
        s[t] += u;
        __syncthreads();
    }
    int incl = s[t];
    int ex = incl - v + boff[blockIdx.x];
    if (i < n) { rowptr[i] = ex; cursor[i] = ex; }
    if (i == n - 1) rowptr[n] = ex + v;
}

__global__ void fill_csr_k(const int* __restrict__ src, const int* __restrict__ dst, int E,
                           int* __restrict__ cursor, int* __restrict__ csr_src) {
    int e = blockIdx.x * 256 + threadIdx.x;
    if (e < E) {
        int d = dst[e];
        int pos = atomicAdd(&cursor[d], 1);
        csr_src[pos] = src[e];
    }
}

// ---------------- GEMM: C[M,N] = A[M,128] @ W[128,N] (no bias) ----------------

template <int N>
__global__ __launch_bounds__(256) void gemm_k(const float* __restrict__ A, const float* __restrict__ W,
                                              float* __restrict__ C, int M) {
    constexpr int TM = 64;
    constexpr int TK = 32;
    constexpr int CT = N / 4;          // col tiles (float4): 32 or 16
    constexpr int RPT = TM * CT / 256; // rows per thread: 8 or 4
    __shared__ float As[TM][TK + 1];   // +1 pad: conflict-free column reads
    __shared__ float Ws[TK][N];

    const int tid = threadIdx.x;
    const int cx = tid % CT;
    const int ry = tid / CT;
    const int rbase = blockIdx.x * TM;

    float acc[RPT][4];
#pragma unroll
    for (int r = 0; r < RPT; r++)
#pragma unroll
        for (int c = 0; c < 4; c++) acc[r][c] = 0.f;

    for (int kk = 0; kk < 128; kk += TK) {
        __syncthreads();
        // stage A tile (scalar LDS writes due to +1 pad)
        for (int idx = tid; idx < TM * (TK / 4); idx += 256) {
            int row = idx >> 3;
            int c4 = idx & 7;
            int gr = rbase + row;
            if (gr >= M) gr = M - 1;
            float4 v = *(const float4*)(A + (size_t)gr * 128 + kk + c4 * 4);
            As[row][c4 * 4 + 0] = v.x;
            As[row][c4 * 4 + 1] = v.y;
            As[row][c4 * 4 + 2] = v.z;
            As[row][c4 * 4 + 3] = v.w;
        }
        // stage W tile
        for (int idx = tid; idx < TK * CT; idx += 256) {
            int row = idx / CT;
            int c4 = idx % CT;
            *(float4*)(&Ws[row][c4 * 4]) = *(const float4*)(W + (size_t)(kk + row) * N + c4 * 4);
        }
        __syncthreads();
        for (int k = 0; k < TK; k++) {
            float4 w = *(const float4*)(&Ws[k][cx * 4]);
#pragma unroll
            for (int r = 0; r < RPT; r++) {
                float a = As[ry * RPT + r][k];
                acc[r][0] += a * w.x;
                acc[r][1] += a * w.y;
                acc[r][2] += a * w.z;
                acc[r][3] += a * w.w;
            }
        }
    }
#pragma unroll
    for (int r = 0; r < RPT; r++) {
        int gr = rbase + ry * RPT + r;
        if (gr < M) {
            float4 o;
            o.x = acc[r][0]; o.y = acc[r][1]; o.z = acc[r][2]; o.w = acc[r][3];
            *(float4*)(C + (size_t)gr * N + cx * 4) = o;
        }
    }
}

// ---------------- Aggregation: out[i] = act(dinv[i]*sum_{s in N(i)} dinv[s]*h[s] + dinv[i]^2*h[i] + b) ----------------

template <int D, bool RELU>
__global__ __launch_bounds__(256) void aggregate_k(const float* __restrict__ h, const float* __restrict__ dinv,
                                                   const int* __restrict__ rowptr, const int* __restrict__ csr_src,
                                                   const float* __restrict__ bias, float* __restrict__ out, int n) {
    int wid = (blockIdx.x * 256 + threadIdx.x) >> 6;  // one wave per node
    int lane = threadIdx.x & 63;
    if (wid >= n) return;
    float di = dinv[wid];
    int e0 = rowptr[wid], e1 = rowptr[wid + 1];
    if (D == 128) {
        float ax = 0.f, ay = 0.f;
        for (int e = e0; e < e1; ++e) {
            int s = csr_src[e];
            float w = dinv[s];
            float2 hv = *(const float2*)(h + (size_t)s * 128 + lane * 2);
            ax += w * hv.x;
            ay += w * hv.y;
        }
        float2 hs = *(const float2*)(h + (size_t)wid * 128 + lane * 2);
        ax = di * ax + di * di * hs.x + bias[lane * 2 + 0];
        ay = di * ay + di * di * hs.y + bias[lane * 2 + 1];
        if (RELU) { ax = fmaxf(ax, 0.f); ay = fmaxf(ay, 0.f); }
        float2 o; o.x = ax; o.y = ay;
        *(float2*)(out + (size_t)wid * 128 + lane * 2) = o;
    } else {
        float a = 0.f;
        for (int e = e0; e < e1; ++e) {
            int s = csr_src[e];
            a += dinv[s] * h[(size_t)s * 64 + lane];
        }
        float hs = h[(size_t)wid * 64 + lane];
        a = di * a + di * di * hs + bias[lane];
        if (RELU) a = fmaxf(a, 0.f);
        out[(size_t)wid * 64 + lane] = a;
    }
}

// ---------------- Pooling (batch is sorted -> per-graph contiguous ranges) ----------------

__global__ void graph_bounds_k(const int* __restrict__ batch, int n, int* __restrict__ gstart) {
    int g = threadIdx.x;
    if (g <= NUM_GRAPHS) {
        int lo = 0, hi = n;
        while (lo < hi) {
            int mid = (lo + hi) >> 1;
            if (batch[mid] < g) lo = mid + 1; else hi = mid;
        }
        gstart[g] = lo;
    }
}

__global__ __launch_bounds__(256) void pool2_k(const float* __restrict__ h, const int* __restrict__ gstart,
                                               float* __restrict__ out) {
    int g = blockIdx.x;
    int s = gstart[g], e = gstart[g + 1];
    int lane = threadIdx.x & 63;
    int row = threadIdx.x >> 6;  // 0..3
    float acc = 0.f;
    for (int i = s + row; i < e; i += 4)
        acc += h[(size_t)i * 64 + lane];
    __shared__ float red[4][64];
    red[row][lane] = acc;
    __syncthreads();
    if (row == 0) {
        float v = red[0][lane] + red[1][lane] + red[2][lane] + red[3][lane];
        int c = e - s;
        out[g * 64 + lane] = v / (float)(c > 1 ? c : 1);
    }
}

// ---------------- launch ----------------

extern "C" void kernel_launch(void* const* d_in, const int* in_sizes, int n_in,
                              void* d_out, int out_size, void* d_ws, size_t ws_size,
                              hipStream_t stream) {
    const float* x = (const float*)d_in[0];
    const int* edge = (const int*)d_in[1];
    const int* batch = (const int*)d_in[2];
    const float* W1 = (const float*)d_in[3];
    const float* b1 = (const float*)d_in[4];
    const float* W2 = (const float*)d_in[5];
    const float* b2 = (const float*)d_in[6];

    const int n = in_sizes[0] / 128;
    const int E = in_sizes[1] / 2;
    const int* esrc = edge;
    const int* edst = edge + E;

    char* ws = (char*)d_ws;
    size_t off = 0;
    auto alloc = [&](size_t bytes) -> char* {
        char* p = ws + off;
        off = (off + bytes + 255) & ~(size_t)255;
        return p;
    };
    int* cnt = (int*)alloc((size_t)n * sizeof(int));
    int* rowptr = (int*)alloc((size_t)(n + 1) * sizeof(int));
    int* cursor = (int*)alloc((size_t)n * sizeof(int));
    int* bsum = (int*)alloc(256 * sizeof(int));
    int* gstart = (int*)alloc((NUM_GRAPHS + 1) * sizeof(int));
    float* dinv = (float*)alloc((size_t)n * sizeof(float));
    int* csr_src = (int*)alloc((size_t)E * sizeof(int));
    float* bufA = (float*)alloc((size_t)n * 128 * sizeof(float));
    float* bufB = (float*)alloc((size_t)n * 128 * sizeof(float));
    (void)ws_size;

    hipMemsetAsync(cnt, 0, (size_t)n * sizeof(int), stream);

    const int eb = (E + 255) / 256;
    const int nb = (n + 255) / 256;  // must be <= 256 for scan_top (n=50000 -> 196)

    count_edges_k<<<eb, 256, 0, stream>>>(edst, E, cnt);
    dinv_k<<<nb, 256, 0, stream>>>(cnt, dinv, n);
    scan_part_k<<<nb, 256, 0, stream>>>(cnt, n, bsum);
    scan_top_k<<<1, 256, 0, stream>>>(bsum, nb);
    scan_final_k<<<nb, 256, 0, stream>>>(cnt, n, bsum, rowptr, cursor);
    fill_csr_k<<<eb, 256, 0, stream>>>(esrc, edst, E, cursor, csr_src);
    graph_bounds_k<<<1, 128, 0, stream>>>(batch, n, gstart);

    // conv1: h1 = x @ W1 ; hagg = relu(aggregate(h1) + b1)
    gemm_k<128><<<(n + 63) / 64, 256, 0, stream>>>(x, W1, bufA, n);
    aggregate_k<128, true><<<(n + 3) / 4, 256, 0, stream>>>(bufA, dinv, rowptr, csr_src, b1, bufB, n);

    // conv2: h2 = hagg @ W2 ; out2 = aggregate(h2) + b2
    gemm_k<64><<<(n + 63) / 64, 256, 0, stream>>>(bufB, W2, bufA, n);
    aggregate_k<64, false><<<(n + 3) / 4, 256, 0, stream>>>(bufA, dinv, rowptr, csr_src, b2, bufB, n);

    // mean pool over graphs (no atomics: batch is sorted)
    pool2_k<<<NUM_GRAPHS, 256, 0, stream>>>(bufB, gstart, (float*)d_out);
}

// Round 3
// 236.016 us; speedup vs baseline: 2.6140x; 1.3469x over previous
//
#include <hip/hip_runtime.h>

constexpr int NUM_GRAPHS = 64;

typedef __attribute__((ext_vector_type(8))) short bf16x8;
typedef __attribute__((ext_vector_type(4))) float f32x4;

__device__ inline unsigned short f2bf(float f) {
    unsigned u = __float_as_uint(f);
    unsigned r = (u + 0x7FFFu + ((u >> 16) & 1u)) >> 16;
    return (unsigned short)r;
}
__device__ inline float bflo(unsigned v) { return __uint_as_float(v << 16); }
__device__ inline float bfhi(unsigned v) { return __uint_as_float(v & 0xFFFF0000u); }

// ---------------- CSR build ----------------

__global__ void count_edges_k(const int* __restrict__ dst, int E, int* __restrict__ cnt) {
    int e = blockIdx.x * 256 + threadIdx.x;
    if (e < E) atomicAdd(&cnt[dst[e]], 1);
}

__global__ void dinv_k(const int* __restrict__ cnt, float* __restrict__ dinv, int n) {
    int i = blockIdx.x * 256 + threadIdx.x;
    if (i < n) dinv[i] = rsqrtf((float)(cnt[i] + 1));  // +1 self-loop
}

__global__ void scan_part_k(const int* __restrict__ cnt, int n, int* __restrict__ bsum) {
    __shared__ int s[256];
    int t = threadIdx.x;
    int i = blockIdx.x * 256 + t;
    s[t] = (i < n) ? cnt[i] : 0;
    __syncthreads();
    for (int off = 128; off > 0; off >>= 1) {
        if (t < off) s[t] += s[t + off];
        __syncthreads();
    }
    if (t == 0) bsum[blockIdx.x] = s[0];
}

__global__ void scan_top_k(int* __restrict__ bsum, int nb) {
    __shared__ int s[256];
    int t = threadIdx.x;
    s[t] = (t < nb) ? bsum[t] : 0;
    __syncthreads();
    for (int off = 1; off < 256; off <<= 1) {
        int v = (t >= off) ? s[t - off] : 0;
        __syncthreads();
        s[t] += v;
        __syncthreads();
    }
    int ex = (t == 0) ? 0 : s[t - 1];
    if (t < nb) bsum[t] = ex;
}

__global__ void scan_final_k(const int* __restrict__ cnt, int n, const int* __restrict__ boff,
                             int* __restrict__ rowptr, int* __restrict__ cursor) {
    __shared__ int s[256];
    int t = threadIdx.x;
    int i = blockIdx.x * 256 + t;
    int v = (i < n) ? cnt[i] : 0;
    s[t] = v;
    __syncthreads();
    for (int off = 1; off < 256; off <<= 1) {
        int u = (t >= off) ? s[t - off] : 0;
        __syncthreads();
        s[t] += u;
        __syncthreads();
    }
    int incl = s[t];
    int ex = incl - v + boff[blockIdx.x];
    if (i < n) { rowptr[i] = ex; cursor[i] = ex; }
    if (i == n - 1) rowptr[n] = ex + v;
}

__global__ void fill_csr_k(const int* __restrict__ src, const int* __restrict__ dst, int E,
                           int* __restrict__ cursor, int* __restrict__ csr_src) {
    int e = blockIdx.x * 256 + threadIdx.x;
    if (e < E) {
        int d = dst[e];
        int pos = atomicAdd(&cursor[d], 1);
        csr_src[pos] = src[e];
    }
}

// ---------------- W transpose+cast: W[128][N] f32 -> Wt[N][128] bf16 ----------------

template <int N>
__global__ void wcast_k(const float* __restrict__ W, unsigned short* __restrict__ Wt) {
    int idx = blockIdx.x * 256 + threadIdx.x;
    if (idx < 128 * N) {
        int k = idx % 128, n = idx / 128;
        Wt[n * 128 + k] = f2bf(W[k * N + n]);
    }
}

// ---------------- MFMA GEMM: P[M,N] = bf16(dinv[row] * (A[M,128] @ W[128,N])) ----------------
// A fp32 (ABF16=false) or bf16-as-ushort (ABF16=true). Wt is [N][128] bf16.

template <int N, bool ABF16>
__global__ __launch_bounds__(256) void mfma_gemm_k(const void* __restrict__ Av, const unsigned short* __restrict__ Wt,
                                                   const float* __restrict__ dinv, unsigned short* __restrict__ P, int M) {
    constexpr int NF = N / 16;     // 8 or 4 col-fragments
    constexpr int LDSK = 136;      // 128 + 8 pad (bf16 elems) -> row stride 272B kills bank conflicts
    __shared__ unsigned short Ws[N * LDSK];
    const int tid = threadIdx.x;

    // stage Wt -> LDS (linear copy, padded rows)
    for (int idx = tid; idx < N * 32; idx += 256) {
        int n = idx >> 5, c = idx & 31;
        *(ushort4*)(&Ws[n * LDSK + c * 4]) = *(const ushort4*)(Wt + n * 128 + c * 4);
    }
    __syncthreads();

    const int lane = tid & 63;
    const int wrow = blockIdx.x * 64 + (tid >> 6) * 16 + (lane & 15);  // A-frag row
    const int k8 = (lane >> 4) * 8;
    const int arow = (wrow < M) ? wrow : (M - 1);

    f32x4 acc[NF] = {};
    const float* Af = (const float*)Av;
    const unsigned short* Ab = (const unsigned short*)Av;

#pragma unroll
    for (int ko = 0; ko < 4; ++ko) {
        const int k0 = ko * 32 + k8;
        bf16x8 a;
        if (ABF16) {
            a = *(const bf16x8*)(Ab + (size_t)arow * 128 + k0);
        } else {
            float4 lo = *(const float4*)(Af + (size_t)arow * 128 + k0);
            float4 hi = *(const float4*)(Af + (size_t)arow * 128 + k0 + 4);
            a[0] = (short)f2bf(lo.x); a[1] = (short)f2bf(lo.y);
            a[2] = (short)f2bf(lo.z); a[3] = (short)f2bf(lo.w);
            a[4] = (short)f2bf(hi.x); a[5] = (short)f2bf(hi.y);
            a[6] = (short)f2bf(hi.z); a[7] = (short)f2bf(hi.w);
        }
#pragma unroll
        for (int nf = 0; nf < NF; ++nf) {
            bf16x8 b = *(const bf16x8*)(&Ws[(nf * 16 + (lane & 15)) * LDSK + k0]);
            acc[nf] = __builtin_amdgcn_mfma_f32_16x16x32_bf16(a, b, acc[nf], 0, 0, 0);
        }
    }

    // epilogue: C row = (lane>>4)*4 + r, col = nf*16 + (lane&15)   [m89 layout]
    const int crow0 = blockIdx.x * 64 + (tid >> 6) * 16 + (lane >> 4) * 4;
    const int ccol = lane & 15;
#pragma unroll
    for (int r = 0; r < 4; ++r) {
        int row = crow0 + r;
        if (row < M) {
            float s = dinv[row];
#pragma unroll
            for (int nf = 0; nf < NF; ++nf)
                P[(size_t)row * N + nf * 16 + ccol] = f2bf(acc[nf][r] * s);
        }
    }
}

// ---------------- Aggregation: out[i] = act(di*(p[i] + sum_{s in N(i)} p[s]) + b), p = dinv*h bf16 ----------------

__global__ __launch_bounds__(256) void agg128_k(const unsigned short* __restrict__ p, const float* __restrict__ dinv,
                                                const int* __restrict__ rowptr, const int* __restrict__ csr_src,
                                                const float* __restrict__ bias, unsigned short* __restrict__ out, int n) {
    int wid = (blockIdx.x * 256 + threadIdx.x) >> 6;  // one wave per node
    int lane = threadIdx.x & 63;
    if (wid >= n) return;
    float di = dinv[wid];
    int e0 = rowptr[wid], e1 = rowptr[wid + 1];
    unsigned v = *(const unsigned*)(p + (size_t)wid * 128 + lane * 2);  // self term
    float ax = bflo(v), ay = bfhi(v);
    for (int e = e0; e < e1; ++e) {
        int s = csr_src[e];
        unsigned w = *(const unsigned*)(p + (size_t)s * 128 + lane * 2);
        ax += bflo(w);
        ay += bfhi(w);
    }
    ax = fmaxf(di * ax + bias[lane * 2 + 0], 0.f);
    ay = fmaxf(di * ay + bias[lane * 2 + 1], 0.f);
    unsigned o = (unsigned)f2bf(ax) | ((unsigned)f2bf(ay) << 16);
    *(unsigned*)(out + (size_t)wid * 128 + lane * 2) = o;
}

__global__ __launch_bounds__(256) void agg64_k(const unsigned short* __restrict__ p, const float* __restrict__ dinv,
                                               const int* __restrict__ rowptr, const int* __restrict__ csr_src,
                                               const float* __restrict__ bias, unsigned short* __restrict__ out, int n) {
    int t = blockIdx.x * 256 + threadIdx.x;
    int node = t >> 5;  // half-wave (32 lanes) per node
    int l = threadIdx.x & 31;
    if (node >= n) return;
    float di = dinv[node];
    int e0 = rowptr[node], e1 = rowptr[node + 1];
    unsigned v = *(const unsigned*)(p + (size_t)node * 64 + l * 2);
    float ax = bflo(v), ay = bfhi(v);
    for (int e = e0; e < e1; ++e) {
        int s = csr_src[e];
        unsigned w = *(const unsigned*)(p + (size_t)s * 64 + l * 2);
        ax += bflo(w);
        ay += bfhi(w);
    }
    ax = di * ax + bias[l * 2 + 0];
    ay = di * ay + bias[l * 2 + 1];
    unsigned o = (unsigned)f2bf(ax) | ((unsigned)f2bf(ay) << 16);
    *(unsigned*)(out + (size_t)node * 64 + l * 2) = o;
}

// ---------------- Pooling (batch sorted -> contiguous per-graph ranges) ----------------

__global__ void graph_bounds_k(const int* __restrict__ batch, int n, int* __restrict__ gstart) {
    int g = threadIdx.x;
    if (g <= NUM_GRAPHS) {
        int lo = 0, hi = n;
        while (lo < hi) {
            int mid = (lo + hi) >> 1;
            if (batch[mid] < g) lo = mid + 1; else hi = mid;
        }
        gstart[g] = lo;
    }
}

__global__ __launch_bounds__(256) void pool2_k(const unsigned short* __restrict__ h, const int* __restrict__ gstart,
                                               float* __restrict__ out) {
    int g = blockIdx.x;
    int s = gstart[g], e = gstart[g + 1];
    int rg = threadIdx.x >> 5;  // 8 row-groups
    int l = threadIdx.x & 31;   // 32 lanes cover 64 cols via uint
    float ax = 0.f, ay = 0.f;
    for (int i = s + rg; i < e; i += 8) {
        unsigned v = *(const unsigned*)(h + (size_t)i * 64 + l * 2);
        ax += bflo(v);
        ay += bfhi(v);
    }
    __shared__ float red[8][64];
    red[rg][l * 2 + 0] = ax;
    red[rg][l * 2 + 1] = ay;
    __syncthreads();
    if (threadIdx.x < 64) {
        int col = threadIdx.x;
        float v = 0.f;
#pragma unroll
        for (int r = 0; r < 8; ++r) v += red[r][col];
        int c = e - s;
        out[g * 64 + col] = v / (float)(c > 1 ? c : 1);
    }
}

// ---------------- launch ----------------

extern "C" void kernel_launch(void* const* d_in, const int* in_sizes, int n_in,
                              void* d_out, int out_size, void* d_ws, size_t ws_size,
                              hipStream_t stream) {
    const float* x = (const float*)d_in[0];
    const int* edge = (const int*)d_in[1];
    const int* batch = (const int*)d_in[2];
    const float* W1 = (const float*)d_in[3];
    const float* b1 = (const float*)d_in[4];
    const float* W2 = (const float*)d_in[5];
    const float* b2 = (const float*)d_in[6];

    const int n = in_sizes[0] / 128;
    const int E = in_sizes[1] / 2;
    const int* esrc = edge;
    const int* edst = edge + E;

    char* ws = (char*)d_ws;
    size_t off = 0;
    auto alloc = [&](size_t bytes) -> char* {
        char* pp = ws + off;
        off = (off + bytes + 255) & ~(size_t)255;
        return pp;
    };
    int* cnt = (int*)alloc((size_t)n * sizeof(int));
    int* rowptr = (int*)alloc((size_t)(n + 1) * sizeof(int));
    int* cursor = (int*)alloc((size_t)n * sizeof(int));
    int* bsum = (int*)alloc(256 * sizeof(int));
    int* gstart = (int*)alloc((NUM_GRAPHS + 1) * sizeof(int));
    float* dinv = (float*)alloc((size_t)n * sizeof(float));
    int* csr_src = (int*)alloc((size_t)E * sizeof(int));
    unsigned short* Wt1 = (unsigned short*)alloc(128 * 128 * sizeof(short));
    unsigned short* Wt2 = (unsigned short*)alloc(128 * 64 * sizeof(short));
    unsigned short* p1 = (unsigned short*)alloc((size_t)n * 128 * sizeof(short));
    unsigned short* hagg = (unsigned short*)alloc((size_t)n * 128 * sizeof(short));
    unsigned short* p2 = (unsigned short*)alloc((size_t)n * 64 * sizeof(short));
    unsigned short* h2 = (unsigned short*)alloc((size_t)n * 64 * sizeof(short));
    (void)ws_size;

    hipMemsetAsync(cnt, 0, (size_t)n * sizeof(int), stream);

    const int eb = (E + 255) / 256;
    const int nb = (n + 255) / 256;  // <= 256 for scan_top (n=50000 -> 196)

    count_edges_k<<<eb, 256, 0, stream>>>(edst, E, cnt);
    dinv_k<<<nb, 256, 0, stream>>>(cnt, dinv, n);
    scan_part_k<<<nb, 256, 0, stream>>>(cnt, n, bsum);
    scan_top_k<<<1, 256, 0, stream>>>(bsum, nb);
    scan_final_k<<<nb, 256, 0, stream>>>(cnt, n, bsum, rowptr, cursor);
    fill_csr_k<<<eb, 256, 0, stream>>>(esrc, edst, E, cursor, csr_src);
    graph_bounds_k<<<1, 128, 0, stream>>>(batch, n, gstart);
    wcast_k<128><<<(128 * 128 + 255) / 256, 256, 0, stream>>>(W1, Wt1);
    wcast_k<64><<<(128 * 64 + 255) / 256, 256, 0, stream>>>(W2, Wt2);

    const int gb = (n + 63) / 64;
    // conv1: p1 = bf16(dinv*(x@W1)); hagg = bf16(relu(di*(p1[i]+sum p1[s]) + b1))
    mfma_gemm_k<128, false><<<gb, 256, 0, stream>>>(x, Wt1, dinv, p1, n);
    agg128_k<<<(n + 3) / 4, 256, 0, stream>>>(p1, dinv, rowptr, csr_src, b1, hagg, n);

    // conv2: p2 = bf16(dinv*(hagg@W2)); h2 = bf16(di*(p2[i]+sum p2[s]) + b2)
    mfma_gemm_k<64, true><<<gb, 256, 0, stream>>>(hagg, Wt2, dinv, p2, n);
    agg64_k<<<(n + 7) / 8, 256, 0, stream>>>(p2, dinv, rowptr, csr_src, b2, h2, n);

    // mean pool
    pool2_k<<<NUM_GRAPHS, 256, 0, stream>>>(h2, gstart, (float*)d_out);
}

// Round 4
// 228.274 us; speedup vs baseline: 2.7026x; 1.0339x over previous
//
#include <hip/hip_runtime.h>

constexpr int NUM_GRAPHS = 64;

typedef __attribute__((ext_vector_type(8))) short bf16x8;
typedef __attribute__((ext_vector_type(4))) float f32x4;

__device__ inline unsigned short f2bf(float f) {
    unsigned u = __float_as_uint(f);
    unsigned r = (u + 0x7FFFu + ((u >> 16) & 1u)) >> 16;
    return (unsigned short)r;
}
__device__ inline float bflo(unsigned v) { return __uint_as_float(v << 16); }
__device__ inline float bfhi(unsigned v) { return __uint_as_float(v & 0xFFFF0000u); }

// ---------------- CSR build ----------------

__global__ void count_edges_k(const int* __restrict__ dst, int E, int* __restrict__ cnt) {
    int e = blockIdx.x * 256 + threadIdx.x;
    if (e < E) atomicAdd(&cnt[dst[e]], 1);
}

__global__ void dinv_k(const int* __restrict__ cnt, float* __restrict__ dinv, int n) {
    int i = blockIdx.x * 256 + threadIdx.x;
    if (i < n) dinv[i] = rsqrtf((float)(cnt[i] + 1));  // +1 self-loop
}

__global__ void scan_part_k(const int* __restrict__ cnt, int n, int* __restrict__ bsum) {
    __shared__ int s[256];
    int t = threadIdx.x;
    int i = blockIdx.x * 256 + t;
    s[t] = (i < n) ? cnt[i] : 0;
    __syncthreads();
    for (int off = 128; off > 0; off >>= 1) {
        if (t < off) s[t] += s[t + off];
        __syncthreads();
    }
    if (t == 0) bsum[blockIdx.x] = s[0];
}

__global__ void scan_top_k(int* __restrict__ bsum, int nb) {
    __shared__ int s[256];
    int t = threadIdx.x;
    s[t] = (t < nb) ? bsum[t] : 0;
    __syncthreads();
    for (int off = 1; off < 256; off <<= 1) {
        int v = (t >= off) ? s[t - off] : 0;
        __syncthreads();
        s[t] += v;
        __syncthreads();
    }
    int ex = (t == 0) ? 0 : s[t - 1];
    if (t < nb) bsum[t] = ex;
}

__global__ void scan_final_k(const int* __restrict__ cnt, int n, const int* __restrict__ boff,
                             int* __restrict__ rowptr, int* __restrict__ cursor) {
    __shared__ int s[256];
    int t = threadIdx.x;
    int i = blockIdx.x * 256 + t;
    int v = (i < n) ? cnt[i] : 0;
    s[t] = v;
    __syncthreads();
    for (int off = 1; off < 256; off <<= 1) {
        int u = (t >= off) ? s[t - off] : 0;
        __syncthreads();
        s[t] += u;
        __syncthreads();
    }
    int incl = s[t];
    int ex = incl - v + boff[blockIdx.x];
    if (i < n) { rowptr[i] = ex; cursor[i] = ex; }
    if (i == n - 1) rowptr[n] = ex + v;
}

__global__ void fill_csr_k(const int* __restrict__ src, const int* __restrict__ dst, int E,
                           int* __restrict__ cursor, int* __restrict__ csr_src) {
    int e = blockIdx.x * 256 + threadIdx.x;
    if (e < E) {
        int d = dst[e];
        int pos = atomicAdd(&cursor[d], 1);
        csr_src[pos] = src[e];
    }
}

// ---------------- W transpose+cast: W[128][N] f32 -> Wt[N][128] bf16 ----------------

template <int N>
__global__ void wcast_k(const float* __restrict__ W, unsigned short* __restrict__ Wt) {
    int idx = blockIdx.x * 256 + threadIdx.x;
    if (idx < 128 * N) {
        int k = idx % 128, n = idx / 128;
        Wt[n * 128 + k] = f2bf(W[k * N + n]);
    }
}

// ---------------- MFMA GEMM: Pc[chunk][M][32] = bf16(dinv[row] * (A[M,128] @ W[128,N])) ----------------
// A fp32 row-major (ACHUNKED=false) or bf16 chunked [4][M][32] (ACHUNKED=true). Wt is [N][128] bf16.

template <int N, bool ACHUNKED>
__global__ __launch_bounds__(256) void mfma_gemm_k(const void* __restrict__ Av, const unsigned short* __restrict__ Wt,
                                                   const float* __restrict__ dinv, unsigned short* __restrict__ Pc, int M) {
    constexpr int NF = N / 16;     // 8 or 4 col-fragments
    constexpr int LDSK = 136;      // 128 + 8 pad (bf16) -> kills bank conflicts on fragment reads
    __shared__ unsigned short Ws[N * LDSK];
    const int tid = threadIdx.x;

    for (int idx = tid; idx < N * 32; idx += 256) {
        int nn = idx >> 5, c = idx & 31;
        *(ushort4*)(&Ws[nn * LDSK + c * 4]) = *(const ushort4*)(Wt + nn * 128 + c * 4);
    }
    __syncthreads();

    const int lane = tid & 63;
    const int wrow = blockIdx.x * 64 + (tid >> 6) * 16 + (lane & 15);  // A-frag row
    const int k8 = (lane >> 4) * 8;
    const int arow = (wrow < M) ? wrow : (M - 1);

    f32x4 acc[NF] = {};
    const float* Af = (const float*)Av;
    const unsigned short* Ab = (const unsigned short*)Av;

#pragma unroll
    for (int ko = 0; ko < 4; ++ko) {
        bf16x8 a;
        if (ACHUNKED) {
            a = *(const bf16x8*)(Ab + ((size_t)ko * M + arow) * 32 + k8);
        } else {
            const int k0 = ko * 32 + k8;
            float4 lo = *(const float4*)(Af + (size_t)arow * 128 + k0);
            float4 hi = *(const float4*)(Af + (size_t)arow * 128 + k0 + 4);
            a[0] = (short)f2bf(lo.x); a[1] = (short)f2bf(lo.y);
            a[2] = (short)f2bf(lo.z); a[3] = (short)f2bf(lo.w);
            a[4] = (short)f2bf(hi.x); a[5] = (short)f2bf(hi.y);
            a[6] = (short)f2bf(hi.z); a[7] = (short)f2bf(hi.w);
        }
        const int k0 = ko * 32 + k8;
#pragma unroll
        for (int nf = 0; nf < NF; ++nf) {
            bf16x8 b = *(const bf16x8*)(&Ws[(nf * 16 + (lane & 15)) * LDSK + k0]);
            acc[nf] = __builtin_amdgcn_mfma_f32_16x16x32_bf16(a, b, acc[nf], 0, 0, 0);
        }
    }

    // epilogue: C row = base + (lane>>4)*4 + r, col = nf*16 + (lane&15); write chunked
    const int crow0 = blockIdx.x * 64 + (tid >> 6) * 16 + (lane >> 4) * 4;
    const int ccol = lane & 15;
#pragma unroll
    for (int r = 0; r < 4; ++r) {
        int row = crow0 + r;
        if (row < M) {
            float s = dinv[row];
#pragma unroll
            for (int nf = 0; nf < NF; ++nf)
                Pc[((size_t)(nf >> 1) * M + row) * 32 + (nf & 1) * 16 + ccol] = f2bf(acc[nf][r] * s);
        }
    }
}

// ---------------- Chunked aggregation ----------------
// pc: [CHUNKS][n][32] bf16 of p = dinv*h. out[i] = act(di*(p[i]+sum_{s in N(i)} p[s]) + b), chunked output.
// chunk pinned to an XCD group via blockIdx&7 (round-robin XCD dispatch): hot set 3.2MB fits 4MB L2.

template <int CHUNKS, bool RELU>
__global__ __launch_bounds__(256) void aggc_k(const unsigned short* __restrict__ pc, const float* __restrict__ dinv,
                                              const int* __restrict__ rowptr, const int* __restrict__ csr_src,
                                              const float* __restrict__ bias, unsigned short* __restrict__ outc, int n) {
    constexpr int SUB = 8 / CHUNKS;            // XCD slots per chunk
    const int b = blockIdx.x;
    const int chunk = (b & 7) / SUB;
    const int part = (b >> 3) * SUB + (b & (SUB - 1));
    const int nid = part * 16 + (threadIdx.x >> 4);  // quarter-wave per node
    const int l = threadIdx.x & 15;
    if (nid >= n) return;

    const unsigned short* p = pc + (size_t)chunk * n * 32;
    float di = dinv[nid];
    int e0 = rowptr[nid], e1 = rowptr[nid + 1];
    unsigned v = *(const unsigned*)(p + (size_t)nid * 32 + l * 2);  // self term
    float ax = bflo(v), ay = bfhi(v);
    for (int e = e0; e < e1; ++e) {
        int s = csr_src[e];
        unsigned w = *(const unsigned*)(p + (size_t)s * 32 + l * 2);
        ax += bflo(w);
        ay += bfhi(w);
    }
    int c0 = chunk * 32 + l * 2;
    ax = di * ax + bias[c0 + 0];
    ay = di * ay + bias[c0 + 1];
    if (RELU) { ax = fmaxf(ax, 0.f); ay = fmaxf(ay, 0.f); }
    unsigned o = (unsigned)f2bf(ax) | ((unsigned)f2bf(ay) << 16);
    *(unsigned*)(outc + ((size_t)chunk * n + nid) * 32 + l * 2) = o;
}

// ---------------- Pooling (batch sorted -> contiguous per-graph ranges) ----------------

__global__ void graph_bounds_k(const int* __restrict__ batch, int n, int* __restrict__ gstart) {
    int g = threadIdx.x;
    if (g <= NUM_GRAPHS) {
        int lo = 0, hi = n;
        while (lo < hi) {
            int mid = (lo + hi) >> 1;
            if (batch[mid] < g) lo = mid + 1; else hi = mid;
        }
        gstart[g] = lo;
    }
}

// h chunked [2][n][32]
__global__ __launch_bounds__(256) void pool2_k(const unsigned short* __restrict__ h, const int* __restrict__ gstart,
                                               float* __restrict__ out, int n) {
    int g = blockIdx.x;
    int s = gstart[g], e = gstart[g + 1];
    int rg = threadIdx.x >> 5;  // 8 row-groups
    int l = threadIdx.x & 31;   // 32 lanes cover 64 cols via uint; chunk = l>>4
    const unsigned short* hc = h + (size_t)(l >> 4) * n * 32;
    float ax = 0.f, ay = 0.f;
    for (int i = s + rg; i < e; i += 8) {
        unsigned v = *(const unsigned*)(hc + (size_t)i * 32 + (l & 15) * 2);
        ax += bflo(v);
        ay += bfhi(v);
    }
    __shared__ float red[8][64];
    red[rg][l * 2 + 0] = ax;
    red[rg][l * 2 + 1] = ay;
    __syncthreads();
    if (threadIdx.x < 64) {
        int col = threadIdx.x;
        float v = 0.f;
#pragma unroll
        for (int r = 0; r < 8; ++r) v += red[r][col];
        int c = e - s;
        out[g * 64 + col] = v / (float)(c > 1 ? c : 1);
    }
}

// ---------------- launch ----------------

extern "C" void kernel_launch(void* const* d_in, const int* in_sizes, int n_in,
                              void* d_out, int out_size, void* d_ws, size_t ws_size,
                              hipStream_t stream) {
    const float* x = (const float*)d_in[0];
    const int* edge = (const int*)d_in[1];
    const int* batch = (const int*)d_in[2];
    const float* W1 = (const float*)d_in[3];
    const float* b1 = (const float*)d_in[4];
    const float* W2 = (const float*)d_in[5];
    const float* b2 = (const float*)d_in[6];

    const int n = in_sizes[0] / 128;
    const int E = in_sizes[1] / 2;
    const int* esrc = edge;
    const int* edst = edge + E;

    char* ws = (char*)d_ws;
    size_t off = 0;
    auto alloc = [&](size_t bytes) -> char* {
        char* pp = ws + off;
        off = (off + bytes + 255) & ~(size_t)255;
        return pp;
    };
    int* cnt = (int*)alloc((size_t)n * sizeof(int));
    int* rowptr = (int*)alloc((size_t)(n + 1) * sizeof(int));
    int* cursor = (int*)alloc((size_t)n * sizeof(int));
    int* bsum = (int*)alloc(256 * sizeof(int));
    int* gstart = (int*)alloc((NUM_GRAPHS + 1) * sizeof(int));
    float* dinv = (float*)alloc((size_t)n * sizeof(float));
    int* csr_src = (int*)alloc((size_t)E * sizeof(int));
    unsigned short* Wt1 = (unsigned short*)alloc(128 * 128 * sizeof(short));
    unsigned short* Wt2 = (unsigned short*)alloc(128 * 64 * sizeof(short));
    unsigned short* p1 = (unsigned short*)alloc((size_t)n * 128 * sizeof(short));   // [4][n][32]
    unsigned short* hagg = (unsigned short*)alloc((size_t)n * 128 * sizeof(short)); // [4][n][32]
    unsigned short* p2 = (unsigned short*)alloc((size_t)n * 64 * sizeof(short));    // [2][n][32]
    unsigned short* h2 = (unsigned short*)alloc((size_t)n * 64 * sizeof(short));    // [2][n][32]
    (void)ws_size;

    hipMemsetAsync(cnt, 0, (size_t)n * sizeof(int), stream);

    const int eb = (E + 255) / 256;
    const int nb = (n + 255) / 256;  // <= 256 for scan_top (n=50000 -> 196)

    count_edges_k<<<eb, 256, 0, stream>>>(edst, E, cnt);
    dinv_k<<<nb, 256, 0, stream>>>(cnt, dinv, n);
    scan_part_k<<<nb, 256, 0, stream>>>(cnt, n, bsum);
    scan_top_k<<<1, 256, 0, stream>>>(bsum, nb);
    scan_final_k<<<nb, 256, 0, stream>>>(cnt, n, bsum, rowptr, cursor);
    fill_csr_k<<<eb, 256, 0, stream>>>(esrc, edst, E, cursor, csr_src);
    graph_bounds_k<<<1, 128, 0, stream>>>(batch, n, gstart);
    wcast_k<128><<<(128 * 128 + 255) / 256, 256, 0, stream>>>(W1, Wt1);
    wcast_k<64><<<(128 * 64 + 255) / 256, 256, 0, stream>>>(W2, Wt2);

    const int gb = (n + 63) / 64;
    const int parts = (n + 15) / 16;                 // node-parts of 16
    const int grid4 = 8 * ((parts + 1) / 2);         // CHUNKS=4: 2 XCD slots/chunk
    const int grid2 = 8 * ((parts + 3) / 4);         // CHUNKS=2: 4 XCD slots/chunk

    // conv1
    mfma_gemm_k<128, false><<<gb, 256, 0, stream>>>(x, Wt1, dinv, p1, n);
    aggc_k<4, true><<<grid4, 256, 0, stream>>>(p1, dinv, rowptr, csr_src, b1, hagg, n);

    // conv2
    mfma_gemm_k<64, true><<<gb, 256, 0, stream>>>(hagg, Wt2, dinv, p2, n);
    aggc_k<2, false><<<grid2, 256, 0, stream>>>(p2, dinv, rowptr, csr_src, b2, h2, n);

    // mean pool
    pool2_k<<<NUM_GRAPHS, 256, 0, stream>>>(h2, gstart, (float*)d_out, n);
}

// Round 5
// 188.387 us; speedup vs baseline: 3.2749x; 1.2117x over previous
//
#include <hip/hip_runtime.h>

constexpr int NUM_GRAPHS = 64;

typedef __attribute__((ext_vector_type(8))) short bf16x8;
typedef __attribute__((ext_vector_type(4))) float f32x4;

__device__ inline unsigned short f2bf(float f) {
    unsigned u = __float_as_uint(f);
    unsigned r = (u + 0x7FFFu + ((u >> 16) & 1u)) >> 16;
    return (unsigned short)r;
}
__device__ inline float bflo(unsigned v) { return __uint_as_float(v << 16); }
__device__ inline float bfhi(unsigned v) { return __uint_as_float(v & 0xFFFF0000u); }

// ---------------- CSR build ----------------

__global__ void count_edges_k(const int* __restrict__ dst, int E, int* __restrict__ cnt) {
    int e = blockIdx.x * 256 + threadIdx.x;
    if (e < E) atomicAdd(&cnt[dst[e]], 1);
}

__global__ void dinv_k(const int* __restrict__ cnt, float* __restrict__ dinv, int n) {
    int i = blockIdx.x * 256 + threadIdx.x;
    if (i < n) dinv[i] = rsqrtf((float)(cnt[i] + 1));  // +1 self-loop
}

__global__ void scan_part_k(const int* __restrict__ cnt, int n, int* __restrict__ bsum) {
    __shared__ int s[256];
    int t = threadIdx.x;
    int i = blockIdx.x * 256 + t;
    s[t] = (i < n) ? cnt[i] : 0;
    __syncthreads();
    for (int off = 128; off > 0; off >>= 1) {
        if (t < off) s[t] += s[t + off];
        __syncthreads();
    }
    if (t == 0) bsum[blockIdx.x] = s[0];
}

__global__ void scan_top_k(int* __restrict__ bsum, int nb) {
    __shared__ int s[256];
    int t = threadIdx.x;
    s[t] = (t < nb) ? bsum[t] : 0;
    __syncthreads();
    for (int off = 1; off < 256; off <<= 1) {
        int v = (t >= off) ? s[t - off] : 0;
        __syncthreads();
        s[t] += v;
        __syncthreads();
    }
    int ex = (t == 0) ? 0 : s[t - 1];
    if (t < nb) bsum[t] = ex;
}

__global__ void scan_final_k(const int* __restrict__ cnt, int n, const int* __restrict__ boff,
                             int* __restrict__ rowptr, int* __restrict__ cursor) {
    __shared__ int s[256];
    int t = threadIdx.x;
    int i = blockIdx.x * 256 + t;
    int v = (i < n) ? cnt[i] : 0;
    s[t] = v;
    __syncthreads();
    for (int off = 1; off < 256; off <<= 1) {
        int u = (t >= off) ? s[t - off] : 0;
        __syncthreads();
        s[t] += u;
        __syncthreads();
    }
    int incl = s[t];
    int ex = incl - v + boff[blockIdx.x];
    if (i < n) { rowptr[i] = ex; cursor[i] = ex; }
    if (i == n - 1) rowptr[n] = ex + v;
}

__global__ void fill_csr_k(const int* __restrict__ src, const int* __restrict__ dst, int E,
                           int* __restrict__ cursor, int* __restrict__ csr_src) {
    int e = blockIdx.x * 256 + threadIdx.x;
    if (e < E) {
        int d = dst[e];
        int pos = atomicAdd(&cursor[d], 1);
        csr_src[pos] = src[e];
    }
}

// ---------------- W transpose+cast: W[128][N] f32 -> Wt[N][128] bf16 ----------------

template <int N>
__global__ void wcast_k(const float* __restrict__ W, unsigned short* __restrict__ Wt) {
    int idx = blockIdx.x * 256 + threadIdx.x;
    if (idx < 128 * N) {
        int k = idx % 128, n = idx / 128;
        Wt[n * 128 + k] = f2bf(W[k * N + n]);
    }
}

// ---------------- MFMA GEMM: Pc[chunk][M][32] = bf16(dinv[row] * (A[M,128] @ W[128,N])) ----------------

template <int N, bool ACHUNKED>
__global__ __launch_bounds__(256) void mfma_gemm_k(const void* __restrict__ Av, const unsigned short* __restrict__ Wt,
                                                   const float* __restrict__ dinv, unsigned short* __restrict__ Pc, int M) {
    constexpr int NF = N / 16;
    constexpr int LDSK = 136;
    __shared__ unsigned short Ws[N * LDSK];
    const int tid = threadIdx.x;

    for (int idx = tid; idx < N * 32; idx += 256) {
        int nn = idx >> 5, c = idx & 31;
        *(ushort4*)(&Ws[nn * LDSK + c * 4]) = *(const ushort4*)(Wt + nn * 128 + c * 4);
    }
    __syncthreads();

    const int lane = tid & 63;
    const int wrow = blockIdx.x * 64 + (tid >> 6) * 16 + (lane & 15);
    const int k8 = (lane >> 4) * 8;
    const int arow = (wrow < M) ? wrow : (M - 1);

    f32x4 acc[NF] = {};
    const float* Af = (const float*)Av;
    const unsigned short* Ab = (const unsigned short*)Av;

#pragma unroll
    for (int ko = 0; ko < 4; ++ko) {
        bf16x8 a;
        if (ACHUNKED) {
            a = *(const bf16x8*)(Ab + ((size_t)ko * M + arow) * 32 + k8);
        } else {
            const int kq = ko * 32 + k8;
            float4 lo = *(const float4*)(Af + (size_t)arow * 128 + kq);
            float4 hi = *(const float4*)(Af + (size_t)arow * 128 + kq + 4);
            a[0] = (short)f2bf(lo.x); a[1] = (short)f2bf(lo.y);
            a[2] = (short)f2bf(lo.z); a[3] = (short)f2bf(lo.w);
            a[4] = (short)f2bf(hi.x); a[5] = (short)f2bf(hi.y);
            a[6] = (short)f2bf(hi.z); a[7] = (short)f2bf(hi.w);
        }
        const int k0 = ko * 32 + k8;
#pragma unroll
        for (int nf = 0; nf < NF; ++nf) {
            bf16x8 b = *(const bf16x8*)(&Ws[(nf * 16 + (lane & 15)) * LDSK + k0]);
            acc[nf] = __builtin_amdgcn_mfma_f32_16x16x32_bf16(a, b, acc[nf], 0, 0, 0);
        }
    }

    const int crow0 = blockIdx.x * 64 + (tid >> 6) * 16 + (lane >> 4) * 4;
    const int ccol = lane & 15;
#pragma unroll
    for (int r = 0; r < 4; ++r) {
        int row = crow0 + r;
        if (row < M) {
            float s = dinv[row];
#pragma unroll
            for (int nf = 0; nf < NF; ++nf)
                Pc[((size_t)(nf >> 1) * M + row) * 32 + (nf & 1) * 16 + ccol] = f2bf(acc[nf][r] * s);
        }
    }
}

// ---------------- Chunked aggregation with batched-ILP gather ----------------
// pc: [CHUNKS][n][32] bf16 of p = dinv*h. out[i] = act(di*(p[i]+sum_{s in N(i)} p[s]) + b).
// Edge loop runs in masked batches of 16: 4x int4 index loads, then 16 independent
// gathers -> two vmcnt waits per 16 edges instead of ~16 serial (idx->gather) chains.

template <int CHUNKS, bool RELU>
__global__ __launch_bounds__(256) void aggc_k(const unsigned short* __restrict__ pc, const float* __restrict__ dinv,
                                              const int* __restrict__ rowptr, const int* __restrict__ csr_src,
                                              const float* __restrict__ bias, unsigned short* __restrict__ outc, int n) {
    constexpr int SUB = 8 / CHUNKS;
    const int b = blockIdx.x;
    const int chunk = (b & 7) / SUB;
    const int part = (b >> 3) * SUB + (b & (SUB - 1));
    const int nid = part * 16 + (threadIdx.x >> 4);  // quarter-wave per node
    const int l = threadIdx.x & 15;
    if (nid >= n) return;

    const unsigned short* p = pc + (size_t)chunk * n * 32;
    float di = dinv[nid];
    int e0 = rowptr[nid], e1 = rowptr[nid + 1];
    unsigned v = *(const unsigned*)(p + (size_t)nid * 32 + l * 2);  // self term
    float ax = bflo(v), ay = bfhi(v);

    const int start = e0 & ~3;  // align for int4 loads; csr_src padded by 16 ints
    for (int base = start; base < e1; base += 16) {
        int idx[16];
#pragma unroll
        for (int j = 0; j < 4; ++j) {
            int4 q = *(const int4*)(csr_src + base + j * 4);
            idx[j * 4 + 0] = q.x; idx[j * 4 + 1] = q.y;
            idx[j * 4 + 2] = q.z; idx[j * 4 + 3] = q.w;
        }
        unsigned w[16];
        bool m[16];
#pragma unroll
        for (int i = 0; i < 16; ++i) {
            int ee = base + i;
            m[i] = (ee >= e0) & (ee < e1);
            int s = m[i] ? idx[i] : nid;
            w[i] = *(const unsigned*)(p + (size_t)s * 32 + l * 2);
        }
#pragma unroll
        for (int i = 0; i < 16; ++i) {
            ax += m[i] ? bflo(w[i]) : 0.f;
            ay += m[i] ? bfhi(w[i]) : 0.f;
        }
    }

    int c0 = chunk * 32 + l * 2;
    ax = di * ax + bias[c0 + 0];
    ay = di * ay + bias[c0 + 1];
    if (RELU) { ax = fmaxf(ax, 0.f); ay = fmaxf(ay, 0.f); }
    unsigned o = (unsigned)f2bf(ax) | ((unsigned)f2bf(ay) << 16);
    *(unsigned*)(outc + ((size_t)chunk * n + nid) * 32 + l * 2) = o;
}

// ---------------- Pooling ----------------

__global__ void graph_bounds_k(const int* __restrict__ batch, int n, int* __restrict__ gstart) {
    int g = threadIdx.x;
    if (g <= NUM_GRAPHS) {
        int lo = 0, hi = n;
        while (lo < hi) {
            int mid = (lo + hi) >> 1;
            if (batch[mid] < g) lo = mid + 1; else hi = mid;
        }
        gstart[g] = lo;
    }
}

// h chunked [2][n][32]
__global__ __launch_bounds__(256) void pool2_k(const unsigned short* __restrict__ h, const int* __restrict__ gstart,
                                               float* __restrict__ out, int n) {
    int g = blockIdx.x;
    int s = gstart[g], e = gstart[g + 1];
    int rg = threadIdx.x >> 5;
    int l = threadIdx.x & 31;
    const unsigned short* hc = h + (size_t)(l >> 4) * n * 32;
    float ax = 0.f, ay = 0.f;
    for (int i = s + rg; i < e; i += 8) {
        unsigned v = *(const unsigned*)(hc + (size_t)i * 32 + (l & 15) * 2);
        ax += bflo(v);
        ay += bfhi(v);
    }
    __shared__ float red[8][64];
    red[rg][l * 2 + 0] = ax;
    red[rg][l * 2 + 1] = ay;
    __syncthreads();
    if (threadIdx.x < 64) {
        int col = threadIdx.x;
        float v = 0.f;
#pragma unroll
        for (int r = 0; r < 8; ++r) v += red[r][col];
        int c = e - s;
        out[g * 64 + col] = v / (float)(c > 1 ? c : 1);
    }
}

// ---------------- launch ----------------

extern "C" void kernel_launch(void* const* d_in, const int* in_sizes, int n_in,
                              void* d_out, int out_size, void* d_ws, size_t ws_size,
                              hipStream_t stream) {
    const float* x = (const float*)d_in[0];
    const int* edge = (const int*)d_in[1];
    const int* batch = (const int*)d_in[2];
    const float* W1 = (const float*)d_in[3];
    const float* b1 = (const float*)d_in[4];
    const float* W2 = (const float*)d_in[5];
    const float* b2 = (const float*)d_in[6];

    const int n = in_sizes[0] / 128;
    const int E = in_sizes[1] / 2;
    const int* esrc = edge;
    const int* edst = edge + E;

    char* ws = (char*)d_ws;
    size_t off = 0;
    auto alloc = [&](size_t bytes) -> char* {
        char* pp = ws + off;
        off = (off + bytes + 255) & ~(size_t)255;
        return pp;
    };
    int* cnt = (int*)alloc((size_t)n * sizeof(int));
    int* rowptr = (int*)alloc((size_t)(n + 1) * sizeof(int));
    int* cursor = (int*)alloc((size_t)n * sizeof(int));
    int* bsum = (int*)alloc(256 * sizeof(int));
    int* gstart = (int*)alloc((NUM_GRAPHS + 1) * sizeof(int));
    float* dinv = (float*)alloc((size_t)n * sizeof(float));
    int* csr_src = (int*)alloc(((size_t)E + 16) * sizeof(int));  // +16 pad for batch loads
    unsigned short* Wt1 = (unsigned short*)alloc(128 * 128 * sizeof(short));
    unsigned short* Wt2 = (unsigned short*)alloc(128 * 64 * sizeof(short));
    unsigned short* p1 = (unsigned short*)alloc((size_t)n * 128 * sizeof(short));   // [4][n][32]
    unsigned short* hagg = (unsigned short*)alloc((size_t)n * 128 * sizeof(short)); // [4][n][32]
    unsigned short* p2 = (unsigned short*)alloc((size_t)n * 64 * sizeof(short));    // [2][n][32]
    unsigned short* h2 = (unsigned short*)alloc((size_t)n * 64 * sizeof(short));    // [2][n][32]
    (void)ws_size;

    hipMemsetAsync(cnt, 0, (size_t)n * sizeof(int), stream);

    const int eb = (E + 255) / 256;
    const int nb = (n + 255) / 256;

    count_edges_k<<<eb, 256, 0, stream>>>(edst, E, cnt);
    dinv_k<<<nb, 256, 0, stream>>>(cnt, dinv, n);
    scan_part_k<<<nb, 256, 0, stream>>>(cnt, n, bsum);
    scan_top_k<<<1, 256, 0, stream>>>(bsum, nb);
    scan_final_k<<<nb, 256, 0, stream>>>(cnt, n, bsum, rowptr, cursor);
    fill_csr_k<<<eb, 256, 0, stream>>>(esrc, edst, E, cursor, csr_src);
    graph_bounds_k<<<1, 128, 0, stream>>>(batch, n, gstart);
    wcast_k<128><<<(128 * 128 + 255) / 256, 256, 0, stream>>>(W1, Wt1);
    wcast_k<64><<<(128 * 64 + 255) / 256, 256, 0, stream>>>(W2, Wt2);

    const int gb = (n + 63) / 64;
    const int parts = (n + 15) / 16;
    const int grid4 = 8 * ((parts + 1) / 2);
    const int grid2 = 8 * ((parts + 3) / 4);

    // conv1
    mfma_gemm_k<128, false><<<gb, 256, 0, stream>>>(x, Wt1, dinv, p1, n);
    aggc_k<4, true><<<grid4, 256, 0, stream>>>(p1, dinv, rowptr, csr_src, b1, hagg, n);

    // conv2
    mfma_gemm_k<64, true><<<gb, 256, 0, stream>>>(hagg, Wt2, dinv, p2, n);
    aggc_k<2, false><<<grid2, 256, 0, stream>>>(p2, dinv, rowptr, csr_src, b2, h2, n);

    // mean pool
    pool2_k<<<NUM_GRAPHS, 256, 0, stream>>>(h2, gstart, (float*)d_out, n);
}

// Round 6
// 186.223 us; speedup vs baseline: 3.3129x; 1.0116x over previous
//
#include <hip/hip_runtime.h>

constexpr int NUM_GRAPHS = 64;

typedef __attribute__((ext_vector_type(8))) short bf16x8;
typedef __attribute__((ext_vector_type(4))) float f32x4;

__device__ inline unsigned short f2bf(float f) {
    unsigned u = __float_as_uint(f);
    unsigned r = (u + 0x7FFFu + ((u >> 16) & 1u)) >> 16;
    return (unsigned short)r;
}
__device__ inline float bflo(unsigned v) { return __uint_as_float(v << 16); }
__device__ inline float bfhi(unsigned v) { return __uint_as_float(v & 0xFFFF0000u); }

// ---------------- init ----------------

__global__ void zero_k(int* __restrict__ p, int n) {
    int i = blockIdx.x * 256 + threadIdx.x;
    if (i < n) p[i] = 0;
}

// ---------------- CSR build ----------------

__global__ void count_edges_k(const int* __restrict__ dst, int E, int* __restrict__ cnt) {
    int e = blockIdx.x * 256 + threadIdx.x;
    if (e < E) atomicAdd(&cnt[dst[e]], 1);
}

__global__ void scan_part_k(const int* __restrict__ cnt, int n, int* __restrict__ bsum) {
    __shared__ int s[256];
    int t = threadIdx.x;
    int i = blockIdx.x * 256 + t;
    s[t] = (i < n) ? cnt[i] : 0;
    __syncthreads();
    for (int off = 128; off > 0; off >>= 1) {
        if (t < off) s[t] += s[t + off];
        __syncthreads();
    }
    if (t == 0) bsum[blockIdx.x] = s[0];
}

// single block; also computes per-graph node ranges (batch is sorted)
__global__ void scan_top_k(int* __restrict__ bsum, int nb,
                           const int* __restrict__ batch, int n, int* __restrict__ gstart) {
    __shared__ int s[256];
    int t = threadIdx.x;
    s[t] = (t < nb) ? bsum[t] : 0;
    __syncthreads();
    for (int off = 1; off < 256; off <<= 1) {
        int v = (t >= off) ? s[t - off] : 0;
        __syncthreads();
        s[t] += v;
        __syncthreads();
    }
    int ex = (t == 0) ? 0 : s[t - 1];
    if (t < nb) bsum[t] = ex;
    // fused graph_bounds
    if (t <= NUM_GRAPHS) {
        int lo = 0, hi = n;
        while (lo < hi) {
            int mid = (lo + hi) >> 1;
            if (batch[mid] < t) lo = mid + 1; else hi = mid;
        }
        gstart[t] = lo;
    }
}

// also computes dinv (fused)
__global__ void scan_final_k(const int* __restrict__ cnt, int n, const int* __restrict__ boff,
                             int* __restrict__ rowptr, int* __restrict__ cursor,
                             float* __restrict__ dinv) {
    __shared__ int s[256];
    int t = threadIdx.x;
    int i = blockIdx.x * 256 + t;
    int v = (i < n) ? cnt[i] : 0;
    s[t] = v;
    __syncthreads();
    for (int off = 1; off < 256; off <<= 1) {
        int u = (t >= off) ? s[t - off] : 0;
        __syncthreads();
        s[t] += u;
        __syncthreads();
    }
    int incl = s[t];
    int ex = incl - v + boff[blockIdx.x];
    if (i < n) {
        rowptr[i] = ex;
        cursor[i] = ex;
        dinv[i] = rsqrtf((float)(v + 1));  // +1 self-loop
    }
    if (i == n - 1) rowptr[n] = ex + v;
}

__global__ void fill_csr_k(const int* __restrict__ src, const int* __restrict__ dst, int E,
                           int* __restrict__ cursor, int* __restrict__ csr_src) {
    int e = blockIdx.x * 256 + threadIdx.x;
    if (e < E) {
        int d = dst[e];
        int pos = atomicAdd(&cursor[d], 1);
        csr_src[pos] = src[e];
    }
}

// ---------------- W transpose+cast (both weights, one launch) ----------------
// W1[128][128] -> Wt1[128][128]^T ; W2[128][64] -> Wt2[64][128]^T

__global__ void wcast_both_k(const float* __restrict__ W1, const float* __restrict__ W2,
                             unsigned short* __restrict__ Wt1, unsigned short* __restrict__ Wt2) {
    int idx = blockIdx.x * 256 + threadIdx.x;
    if (idx < 128 * 128) {
        int k = idx % 128, c = idx / 128;
        Wt1[c * 128 + k] = f2bf(W1[k * 128 + c]);
    } else if (idx < 128 * 128 + 128 * 64) {
        int j = idx - 128 * 128;
        int k = j % 128, c = j / 128;
        Wt2[c * 128 + k] = f2bf(W2[k * 64 + c]);
    }
}

// ---------------- MFMA GEMM: Pc[chunk][M][32] = bf16(dinv[row] * (A[M,128] @ W[128,N])) ----------------

template <int N, bool ACHUNKED>
__global__ __launch_bounds__(256) void mfma_gemm_k(const void* __restrict__ Av, const unsigned short* __restrict__ Wt,
                                                   const float* __restrict__ dinv, unsigned short* __restrict__ Pc, int M) {
    constexpr int NF = N / 16;
    constexpr int LDSK = 136;
    __shared__ unsigned short Ws[N * LDSK];
    const int tid = threadIdx.x;

    for (int idx = tid; idx < N * 32; idx += 256) {
        int nn = idx >> 5, c = idx & 31;
        *(ushort4*)(&Ws[nn * LDSK + c * 4]) = *(const ushort4*)(Wt + nn * 128 + c * 4);
    }
    __syncthreads();

    const int lane = tid & 63;
    const int wrow = blockIdx.x * 64 + (tid >> 6) * 16 + (lane & 15);
    const int k8 = (lane >> 4) * 8;
    const int arow = (wrow < M) ? wrow : (M - 1);

    f32x4 acc[NF] = {};
    const float* Af = (const float*)Av;
    const unsigned short* Ab = (const unsigned short*)Av;

#pragma unroll
    for (int ko = 0; ko < 4; ++ko) {
        bf16x8 a;
        if (ACHUNKED) {
            a = *(const bf16x8*)(Ab + ((size_t)ko * M + arow) * 32 + k8);
        } else {
            const int kq = ko * 32 + k8;
            float4 lo = *(const float4*)(Af + (size_t)arow * 128 + kq);
            float4 hi = *(const float4*)(Af + (size_t)arow * 128 + kq + 4);
            a[0] = (short)f2bf(lo.x); a[1] = (short)f2bf(lo.y);
            a[2] = (short)f2bf(lo.z); a[3] = (short)f2bf(lo.w);
            a[4] = (short)f2bf(hi.x); a[5] = (short)f2bf(hi.y);
            a[6] = (short)f2bf(hi.z); a[7] = (short)f2bf(hi.w);
        }
        const int k0 = ko * 32 + k8;
#pragma unroll
        for (int nf = 0; nf < NF; ++nf) {
            bf16x8 b = *(const bf16x8*)(&Ws[(nf * 16 + (lane & 15)) * LDSK + k0]);
            acc[nf] = __builtin_amdgcn_mfma_f32_16x16x32_bf16(a, b, acc[nf], 0, 0, 0);
        }
    }

    const int crow0 = blockIdx.x * 64 + (tid >> 6) * 16 + (lane >> 4) * 4;
    const int ccol = lane & 15;
#pragma unroll
    for (int r = 0; r < 4; ++r) {
        int row = crow0 + r;
        if (row < M) {
            float s = dinv[row];
#pragma unroll
            for (int nf = 0; nf < NF; ++nf)
                Pc[((size_t)(nf >> 1) * M + row) * 32 + (nf & 1) * 16 + ccol] = f2bf(acc[nf][r] * s);
        }
    }
}

// ---------------- Chunked aggregation with batched-ILP gather ----------------

template <int CHUNKS, bool RELU>
__global__ __launch_bounds__(256) void aggc_k(const unsigned short* __restrict__ pc, const float* __restrict__ dinv,
                                              const int* __restrict__ rowptr, const int* __restrict__ csr_src,
                                              const float* __restrict__ bias, unsigned short* __restrict__ outc, int n) {
    constexpr int SUB = 8 / CHUNKS;
    const int b = blockIdx.x;
    const int chunk = (b & 7) / SUB;
    const int part = (b >> 3) * SUB + (b & (SUB - 1));
    const int nid = part * 16 + (threadIdx.x >> 4);  // quarter-wave per node
    const int l = threadIdx.x & 15;
    if (nid >= n) return;

    const unsigned short* p = pc + (size_t)chunk * n * 32;
    float di = dinv[nid];
    int e0 = rowptr[nid], e1 = rowptr[nid + 1];
    unsigned v = *(const unsigned*)(p + (size_t)nid * 32 + l * 2);  // self term
    float ax = bflo(v), ay = bfhi(v);

    const int start = e0 & ~3;  // align for int4 loads; csr_src padded by 16 ints
    for (int base = start; base < e1; base += 16) {
        int idx[16];
#pragma unroll
        for (int j = 0; j < 4; ++j) {
            int4 q = *(const int4*)(csr_src + base + j * 4);
            idx[j * 4 + 0] = q.x; idx[j * 4 + 1] = q.y;
            idx[j * 4 + 2] = q.z; idx[j * 4 + 3] = q.w;
        }
        unsigned w[16];
        bool m[16];
#pragma unroll
        for (int i = 0; i < 16; ++i) {
            int ee = base + i;
            m[i] = (ee >= e0) & (ee < e1);
            int s = m[i] ? idx[i] : nid;
            w[i] = *(const unsigned*)(p + (size_t)s * 32 + l * 2);
        }
#pragma unroll
        for (int i = 0; i < 16; ++i) {
            ax += m[i] ? bflo(w[i]) : 0.f;
            ay += m[i] ? bfhi(w[i]) : 0.f;
        }
    }

    int c0 = chunk * 32 + l * 2;
    ax = di * ax + bias[c0 + 0];
    ay = di * ay + bias[c0 + 1];
    if (RELU) { ax = fmaxf(ax, 0.f); ay = fmaxf(ay, 0.f); }
    unsigned o = (unsigned)f2bf(ax) | ((unsigned)f2bf(ay) << 16);
    *(unsigned*)(outc + ((size_t)chunk * n + nid) * 32 + l * 2) = o;
}

// ---------------- Pooling (h chunked [2][n][32]) ----------------

__global__ __launch_bounds__(256) void pool2_k(const unsigned short* __restrict__ h, const int* __restrict__ gstart,
                                               float* __restrict__ out, int n) {
    int g = blockIdx.x;
    int s = gstart[g], e = gstart[g + 1];
    int rg = threadIdx.x >> 5;
    int l = threadIdx.x & 31;
    const unsigned short* hc = h + (size_t)(l >> 4) * n * 32;
    float ax = 0.f, ay = 0.f;
    for (int i = s + rg; i < e; i += 8) {
        unsigned v = *(const unsigned*)(hc + (size_t)i * 32 + (l & 15) * 2);
        ax += bflo(v);
        ay += bfhi(v);
    }
    __shared__ float red[8][64];
    red[rg][l * 2 + 0] = ax;
    red[rg][l * 2 + 1] = ay;
    __syncthreads();
    if (threadIdx.x < 64) {
        int col = threadIdx.x;
        float v = 0.f;
#pragma unroll
        for (int r = 0; r < 8; ++r) v += red[r][col];
        int c = e - s;
        out[g * 64 + col] = v / (float)(c > 1 ? c : 1);
    }
}

// ---------------- launch ----------------

extern "C" void kernel_launch(void* const* d_in, const int* in_sizes, int n_in,
                              void* d_out, int out_size, void* d_ws, size_t ws_size,
                              hipStream_t stream) {
    const float* x = (const float*)d_in[0];
    const int* edge = (const int*)d_in[1];
    const int* batch = (const int*)d_in[2];
    const float* W1 = (const float*)d_in[3];
    const float* b1 = (const float*)d_in[4];
    const float* W2 = (const float*)d_in[5];
    const float* b2 = (const float*)d_in[6];

    const int n = in_sizes[0] / 128;
    const int E = in_sizes[1] / 2;
    const int* esrc = edge;
    const int* edst = edge + E;

    char* ws = (char*)d_ws;
    size_t off = 0;
    auto alloc = [&](size_t bytes) -> char* {
        char* pp = ws + off;
        off = (off + bytes + 255) & ~(size_t)255;
        return pp;
    };
    int* cnt = (int*)alloc((size_t)n * sizeof(int));
    int* rowptr = (int*)alloc((size_t)(n + 1) * sizeof(int));
    int* cursor = (int*)alloc((size_t)n * sizeof(int));
    int* bsum = (int*)alloc(256 * sizeof(int));
    int* gstart = (int*)alloc((NUM_GRAPHS + 1) * sizeof(int));
    float* dinv = (float*)alloc((size_t)n * sizeof(float));
    int* csr_src = (int*)alloc(((size_t)E + 16) * sizeof(int));  // +16 pad for batch loads
    unsigned short* Wt1 = (unsigned short*)alloc(128 * 128 * sizeof(short));
    unsigned short* Wt2 = (unsigned short*)alloc(128 * 64 * sizeof(short));
    unsigned short* p1 = (unsigned short*)alloc((size_t)n * 128 * sizeof(short));   // [4][n][32]
    unsigned short* hagg = (unsigned short*)alloc((size_t)n * 128 * sizeof(short)); // [4][n][32]
    unsigned short* p2 = (unsigned short*)alloc((size_t)n * 64 * sizeof(short));    // [2][n][32]
    unsigned short* h2 = (unsigned short*)alloc((size_t)n * 64 * sizeof(short));    // [2][n][32]
    (void)ws_size;

    const int eb = (E + 255) / 256;
    const int nb = (n + 255) / 256;  // <= 256 for scan_top (n=50000 -> 196)

    zero_k<<<nb, 256, 0, stream>>>(cnt, n);
    count_edges_k<<<eb, 256, 0, stream>>>(edst, E, cnt);
    scan_part_k<<<nb, 256, 0, stream>>>(cnt, n, bsum);
    scan_top_k<<<1, 256, 0, stream>>>(bsum, nb, batch, n, gstart);
    scan_final_k<<<nb, 256, 0, stream>>>(cnt, n, bsum, rowptr, cursor, dinv);
    fill_csr_k<<<eb, 256, 0, stream>>>(esrc, edst, E, cursor, csr_src);
    wcast_both_k<<<(128 * 192 + 255) / 256, 256, 0, stream>>>(W1, W2, Wt1, Wt2);

    const int gb = (n + 63) / 64;
    const int parts = (n + 15) / 16;
    const int grid4 = 8 * ((parts + 1) / 2);
    const int grid2 = 8 * ((parts + 3) / 4);

    // conv1
    mfma_gemm_k<128, false><<<gb, 256, 0, stream>>>(x, Wt1, dinv, p1, n);
    aggc_k<4, true><<<grid4, 256, 0, stream>>>(p1, dinv, rowptr, csr_src, b1, hagg, n);

    // conv2
    mfma_gemm_k<64, true><<<gb, 256, 0, stream>>>(hagg, Wt2, dinv, p2, n);
    aggc_k<2, false><<<grid2, 256, 0, stream>>>(p2, dinv, rowptr, csr_src, b2, h2, n);

    // mean pool
    pool2_k<<<NUM_GRAPHS, 256, 0, stream>>>(h2, gstart, (float*)d_out, n);
}